// Round 2
// baseline (407.779 us; speedup 1.0000x reference)
//
#include <hip/hip_runtime.h>
#include <math.h>

#define T_TOK 2048
#define HIDDEN 2048
#define NH 16
#define NKV 8
#define DH 128

typedef unsigned short u16;
typedef __attribute__((ext_vector_type(8))) short bf16x8;
typedef __attribute__((ext_vector_type(4))) float f32x4;

__device__ __forceinline__ u16 f2bf(float f) {
  union { float f; unsigned u; } x; x.f = f;
  unsigned r = (x.u + 0x7fffu + ((x.u >> 16) & 1u)) >> 16;
  return (u16)r;
}

__device__ __forceinline__ void gload16(const void* g, void* l) {
  __builtin_amdgcn_global_load_lds((const __attribute__((address_space(1))) void*)g,
                                   (__attribute__((address_space(3))) void*)l,
                                   16, 0, 0);
}

// ---------------------------------------------------------------- elementwise
__global__ __launch_bounds__(256) void f32_to_bf16_vec(const float* __restrict__ in,
                                                       u16* __restrict__ out, int n4) {
  int i = blockIdx.x * blockDim.x + threadIdx.x;
  if (i < n4) {
    float4 v = ((const float4*)in)[i];
    ushort4 o;
    o.x = f2bf(v.x); o.y = f2bf(v.y); o.z = f2bf(v.z); o.w = f2bf(v.w);
    ((ushort4*)out)[i] = o;
  }
}

// out[c][r] = bf16(in[r][c]) ; in is R x Cdim row-major
__global__ __launch_bounds__(256) void transpose_f32_bf16(const float* __restrict__ in,
                                                          u16* __restrict__ out,
                                                          int R, int Cdim) {
  __shared__ float tile[64][65];
  const int c0 = blockIdx.x * 64, r0 = blockIdx.y * 64;
  const int tx = threadIdx.x & 63, ty = threadIdx.x >> 6;
#pragma unroll
  for (int i = 0; i < 64; i += 4)
    tile[ty + i][tx] = in[(size_t)(r0 + ty + i) * Cdim + c0 + tx];
  __syncthreads();
#pragma unroll
  for (int i = 0; i < 64; i += 4)
    out[(size_t)(c0 + ty + i) * R + r0 + tx] = f2bf(tile[tx][ty + i]);
}

// V slice of qkv (fp32 [T][4096], cols 3072..4095) -> Vt bf16 [kvh][d][t]
__global__ __launch_bounds__(256) void v_transpose(const float* __restrict__ qkv,
                                                   u16* __restrict__ Vt) {
  __shared__ float tile[64][65];
  const int h = blockIdx.x, t0 = blockIdx.y * 64, d0 = blockIdx.z * 64;
  const int tx = threadIdx.x & 63, ty = threadIdx.x >> 6;
#pragma unroll
  for (int i = 0; i < 64; i += 4)
    tile[ty + i][tx] = qkv[(size_t)(t0 + ty + i) * 4096 + (NH + NKV) * DH + h * DH + d0 + tx];
  __syncthreads();
#pragma unroll
  for (int i = 0; i < 64; i += 4)
    Vt[((size_t)h * DH + d0 + ty + i) * T_TOK + t0 + tx] = f2bf(tile[tx][ty + i]);
}

// ------------------------------------------------- per-head RMSNorm + RoPE
__global__ __launch_bounds__(64) void qk_norm_rope(const float* __restrict__ qkv,
                                                   const int* __restrict__ pos,
                                                   const float* __restrict__ qw,
                                                   const float* __restrict__ kw,
                                                   u16* __restrict__ Qg,
                                                   u16* __restrict__ Kg) {
  const int t = blockIdx.x, slot = blockIdx.y, j = threadIdx.x;
  const float* src = qkv + (size_t)t * 4096 + slot * 128;
  float x1 = src[j], x2 = src[j + 64];
  float ss = x1 * x1 + x2 * x2;
#pragma unroll
  for (int m = 1; m < 64; m <<= 1) ss += __shfl_xor(ss, m);
  float r = rsqrtf(ss * (1.0f / 128.0f) + 1e-6f);
  const bool isq = slot < NH;
  const float* w = isq ? qw : kw;
  float xn1 = x1 * r * w[j], xn2 = x2 * r * w[j + 64];
  float fp = (float)pos[t];
  float inv_freq = exp2f(-(float)j * (13.287712379549449f / 64.0f)); // 10000^(-j/64)
  float ang = fp * inv_freq;
  float sn, cs;
  sincosf(ang, &sn, &cs);
  float o1 = xn1 * cs - xn2 * sn;
  float o2 = xn2 * cs + xn1 * sn;
  if (isq) {
    size_t b = ((size_t)slot * T_TOK + t) * DH;
    Qg[b + j] = f2bf(o1); Qg[b + 64 + j] = f2bf(o2);
  } else {
    size_t b = ((size_t)(slot - NH) * T_TOK + t) * DH;
    Kg[b + j] = f2bf(o1); Kg[b + 64 + j] = f2bf(o2);
  }
}

// ------------------------------------------------------------------- GEMM
// C[M][N] fp32 = A[M][K] bf16 row-major  x  Bt[N][K] bf16 row-major (B^T).
__global__ __launch_bounds__(256) void gemm_bf16(const u16* __restrict__ A,
                                                 const u16* __restrict__ Bt,
                                                 float* __restrict__ C,
                                                 int M, int N, int K) {
  __shared__ u16 Alds[128 * 32];
  __shared__ u16 Blds[128 * 32];
  const int m0 = blockIdx.y * 128, n0 = blockIdx.x * 128;
  const int wave = threadIdx.x >> 6, lane = threadIdx.x & 63;
  const int l15 = lane & 15, quad = lane >> 4;
  const int wr = wave >> 1, wc = wave & 1;

  const f32x4 zero = {0.f, 0.f, 0.f, 0.f};
  f32x4 acc[4][4];
#pragma unroll
  for (int i = 0; i < 4; ++i)
#pragma unroll
    for (int j = 0; j < 4; ++j) acc[i][j] = zero;

  for (int k0 = 0; k0 < K; k0 += 32) {
    __syncthreads();
#pragma unroll
    for (int c = 0; c < 2; ++c) {
      int chunk = wave * 2 + c;
      int slot = chunk * 64 + lane;   // 16B slots, 4 per row of 32 bf16
      int row = slot >> 2;
      int g = (slot & 3) ^ (row & 3); // swizzled source group
      gload16(A + (size_t)(m0 + row) * K + k0 + g * 8, &Alds[chunk * 512]);
      gload16(Bt + (size_t)(n0 + row) * K + k0 + g * 8, &Blds[chunk * 512]);
    }
    __syncthreads();
    bf16x8 af[4], bfr[4];
#pragma unroll
    for (int mt = 0; mt < 4; ++mt) {
      int r = wr * 64 + mt * 16 + l15;
      af[mt] = *(const bf16x8*)&Alds[r * 32 + ((quad ^ (r & 3)) * 8)];
    }
#pragma unroll
    for (int nt = 0; nt < 4; ++nt) {
      int r = wc * 64 + nt * 16 + l15;
      bfr[nt] = *(const bf16x8*)&Blds[r * 32 + ((quad ^ (r & 3)) * 8)];
    }
#pragma unroll
    for (int mt = 0; mt < 4; ++mt)
#pragma unroll
      for (int nt = 0; nt < 4; ++nt)
        acc[mt][nt] = __builtin_amdgcn_mfma_f32_16x16x32_bf16(af[mt], bfr[nt], acc[mt][nt], 0, 0, 0);
  }
#pragma unroll
  for (int mt = 0; mt < 4; ++mt)
#pragma unroll
    for (int nt = 0; nt < 4; ++nt)
#pragma unroll
      for (int r = 0; r < 4; ++r)
        C[(size_t)(m0 + wr * 64 + mt * 16 + quad * 4 + r) * N + n0 + wc * 64 + nt * 16 + l15] =
            acc[mt][nt][r];
}

// ------------------------------------------------------------- flash attn
// Barrier-free: K/V fragments loaded DIRECTLY global->register (16B contiguous
// per lane; 4 waves of a block share the same K/V tile via L1). Only the
// wave-local P C-layout->A-layout round-trip uses LDS (no barrier needed).
// Grid 512 = 16 heads x 32 q-tiles, longest tile first (p = 31 - b>>4) so the
// causal triangle backfills.
__global__ __launch_bounds__(256) void attn_kernel(const u16* __restrict__ Qg,
                                                   const u16* __restrict__ Kg,
                                                   const u16* __restrict__ Vtg,
                                                   u16* __restrict__ Og) {
  __shared__ u16 Plds[4][16 * 72];     // per-wave P, padded stride 72
  const int b = blockIdx.x;
  const int h = b & 15;
  const int p = 31 - (b >> 4);         // q-tile, longest-first
  const int kvh = h >> 1;              // GQA group = 2
  const int wave = threadIdx.x >> 6, lane = threadIdx.x & 63;
  const int l15 = lane & 15, quad = lane >> 4;
  const u16* Qh = Qg + (size_t)h * T_TOK * DH;
  const u16* Kh = Kg + (size_t)kvh * T_TOK * DH;
  const u16* Vh = Vtg + (size_t)kvh * DH * T_TOK;
  u16* Pw = &Plds[wave][0];
  const float CSC = 0.088388347648318447f * 1.4426950408889634f; // scale*log2e
  const f32x4 zero = {0.f, 0.f, 0.f, 0.f};
  const int qrow0 = p * 64 + wave * 16;   // wave's 16 q rows

  bf16x8 qf[4];
#pragma unroll
  for (int ks = 0; ks < 4; ++ks)
    qf[ks] = *(const bf16x8*)(Qh + (size_t)(qrow0 + l15) * DH + ks * 32 + quad * 8);

  f32x4 oacc[8];
#pragma unroll
  for (int i = 0; i < 8; ++i) oacc[i] = zero;
  float m_i[4] = {-INFINITY, -INFINITY, -INFINITY, -INFINITY};
  float l_i[4] = {0.f, 0.f, 0.f, 0.f};

  for (int j = 0; j <= p; ++j) {
    const u16* Kt = Kh + (size_t)j * 64 * DH;
    const u16* Vt = Vh + (size_t)j * 64;

    // S = Q K^T  (K B-fragment: lane l15 = key s, 16B contiguous in d)
    f32x4 sacc[4];
#pragma unroll
    for (int nt = 0; nt < 4; ++nt) sacc[nt] = zero;
#pragma unroll
    for (int nt = 0; nt < 4; ++nt) {
#pragma unroll
      for (int ks = 0; ks < 4; ++ks) {
        bf16x8 kf = *(const bf16x8*)(Kt + (size_t)(nt * 16 + l15) * DH + ks * 32 + quad * 8);
        sacc[nt] = __builtin_amdgcn_mfma_f32_16x16x32_bf16(qf[ks], kf, sacc[nt], 0, 0, 0);
      }
    }

    if (j == p) {  // diagonal tile: causal mask
#pragma unroll
      for (int nt = 0; nt < 4; ++nt)
#pragma unroll
        for (int r = 0; r < 4; ++r) {
          int col = j * 64 + nt * 16 + l15;
          int row = qrow0 + quad * 4 + r;
          if (col > row) sacc[nt][r] = -INFINITY;
        }
    }

    // online softmax (rows = quad*4+r, reduce across 16-lane col group)
    float mx[4];
#pragma unroll
    for (int r = 0; r < 4; ++r)
      mx[r] = fmaxf(fmaxf(sacc[0][r], sacc[1][r]), fmaxf(sacc[2][r], sacc[3][r]));
#pragma unroll
    for (int msk = 1; msk < 16; msk <<= 1)
#pragma unroll
      for (int r = 0; r < 4; ++r) mx[r] = fmaxf(mx[r], __shfl_xor(mx[r], msk));

    float alpha[4], lsum[4];
#pragma unroll
    for (int r = 0; r < 4; ++r) {
      float mn = fmaxf(m_i[r], mx[r]);
      alpha[r] = exp2f((m_i[r] - mn) * CSC);
      m_i[r] = mn;
      lsum[r] = 0.f;
    }
#pragma unroll
    for (int nt = 0; nt < 4; ++nt)
#pragma unroll
      for (int r = 0; r < 4; ++r) {
        float pv = exp2f((sacc[nt][r] - m_i[r]) * CSC);
        lsum[r] += pv;
        Pw[(quad * 4 + r) * 72 + nt * 16 + l15] = f2bf(pv);
      }
#pragma unroll
    for (int msk = 1; msk < 16; msk <<= 1)
#pragma unroll
      for (int r = 0; r < 4; ++r) lsum[r] += __shfl_xor(lsum[r], msk);
#pragma unroll
    for (int r = 0; r < 4; ++r) l_i[r] = l_i[r] * alpha[r] + lsum[r];
    {
      f32x4 av = {alpha[0], alpha[1], alpha[2], alpha[3]};
#pragma unroll
      for (int ot = 0; ot < 8; ++ot) oacc[ot] *= av;
    }

    // O += P V  (V B-fragment: lane l15 = d col, 16B contiguous in t)
    bf16x8 pf[2];
#pragma unroll
    for (int ks = 0; ks < 2; ++ks)
      pf[ks] = *(const bf16x8*)&Pw[l15 * 72 + ks * 32 + quad * 8];
#pragma unroll
    for (int ot = 0; ot < 8; ++ot) {
#pragma unroll
      for (int ks = 0; ks < 2; ++ks) {
        bf16x8 vf = *(const bf16x8*)(Vt + (size_t)(ot * 16 + l15) * T_TOK + ks * 32 + quad * 8);
        oacc[ot] = __builtin_amdgcn_mfma_f32_16x16x32_bf16(pf[ks], vf, oacc[ot], 0, 0, 0);
      }
    }
  }

  // epilogue: O/l -> bf16 [t][h*128+d]
  float rl[4];
#pragma unroll
  for (int r = 0; r < 4; ++r) rl[r] = 1.0f / l_i[r];
#pragma unroll
  for (int ot = 0; ot < 8; ++ot)
#pragma unroll
    for (int r = 0; r < 4; ++r) {
      int row = qrow0 + quad * 4 + r;
      Og[(size_t)row * (NH * DH) + h * DH + ot * 16 + l15] = f2bf(oacc[ot][r] * rl[r]);
    }
}

// ------------------------------------------------------------------ launch
extern "C" void kernel_launch(void* const* d_in, const int* in_sizes, int n_in,
                              void* d_out, int out_size, void* d_ws, size_t ws_size,
                              hipStream_t stream) {
  (void)in_sizes; (void)n_in; (void)out_size; (void)ws_size;
  const int* positions = (const int*)d_in[0];
  const float* hidden  = (const float*)d_in[1];
  const float* w_qkv   = (const float*)d_in[2];
  const float* w_o     = (const float*)d_in[3];
  const float* q_norm  = (const float*)d_in[4];
  const float* k_norm  = (const float*)d_in[5];
  float* out = (float*)d_out;

  char* ws = (char*)d_ws;
  u16*   Xb    = (u16*)(ws);                          //  8 MB  bf16 hidden [T][HID]
  u16*   WqkvT = (u16*)(ws + ( 8ull << 20));          // 16 MB  bf16 [4096][2048]
  u16*   WoT   = (u16*)(ws + (24ull << 20));          //  8 MB  bf16 [2048][2048]
  float* QKV   = (float*)(ws + (32ull << 20));        // 32 MB  fp32 [T][4096]
  u16*   Qg    = (u16*)(ws + (64ull << 20));          //  8 MB  bf16 [NH][T][D]
  u16*   Kg    = (u16*)(ws + (72ull << 20));          //  4 MB  bf16 [NKV][T][D]
  u16*   Vt    = (u16*)(ws + (76ull << 20));          //  4 MB  bf16 [NKV][D][T]
  u16*   AttnO = (u16*)(ws + (80ull << 20));          //  8 MB  bf16 [T][NH*D]

  f32_to_bf16_vec<<<dim3((T_TOK * HIDDEN / 4 + 255) / 256), 256, 0, stream>>>(
      hidden, Xb, T_TOK * HIDDEN / 4);
  transpose_f32_bf16<<<dim3(4096 / 64, HIDDEN / 64), 256, 0, stream>>>(w_qkv, WqkvT, HIDDEN, 4096);
  transpose_f32_bf16<<<dim3(HIDDEN / 64, 2048 / 64), 256, 0, stream>>>(w_o, WoT, 2048, HIDDEN);

  gemm_bf16<<<dim3(4096 / 128, T_TOK / 128), 256, 0, stream>>>(Xb, WqkvT, QKV, T_TOK, 4096, HIDDEN);

  qk_norm_rope<<<dim3(T_TOK, NH + NKV), 64, 0, stream>>>(QKV, positions, q_norm, k_norm, Qg, Kg);
  v_transpose<<<dim3(NKV, T_TOK / 64, DH / 64), 256, 0, stream>>>(QKV, Vt);

  attn_kernel<<<dim3(512), 256, 0, stream>>>(Qg, Kg, Vt, AttnO);

  gemm_bf16<<<dim3(HIDDEN / 128, T_TOK / 128), 256, 0, stream>>>(AttnO, WoT, out, T_TOK, HIDDEN, NH * DH);
}

// Round 3
// 300.197 us; speedup vs baseline: 1.3584x; 1.3584x over previous
//
#include <hip/hip_runtime.h>
#include <math.h>

#define T_TOK 2048
#define HIDDEN 2048
#define NH 16
#define NKV 8
#define DH 128

typedef unsigned short u16;
typedef __attribute__((ext_vector_type(8))) short bf16x8;
typedef __attribute__((ext_vector_type(4))) float f32x4;

__device__ __forceinline__ u16 f2bf(float f) {
  union { float f; unsigned u; } x; x.f = f;
  unsigned r = (x.u + 0x7fffu + ((x.u >> 16) & 1u)) >> 16;
  return (u16)r;
}

__device__ __forceinline__ void gload16(const void* g, void* l) {
  __builtin_amdgcn_global_load_lds((const __attribute__((address_space(1))) void*)g,
                                   (__attribute__((address_space(3))) void*)l,
                                   16, 0, 0);
}

// ---------------------------------------------------------------- elementwise
__global__ __launch_bounds__(256) void f32_to_bf16_vec(const float* __restrict__ in,
                                                       u16* __restrict__ out, int n4) {
  int i = blockIdx.x * blockDim.x + threadIdx.x;
  if (i < n4) {
    float4 v = ((const float4*)in)[i];
    ushort4 o;
    o.x = f2bf(v.x); o.y = f2bf(v.y); o.z = f2bf(v.z); o.w = f2bf(v.w);
    ((ushort4*)out)[i] = o;
  }
}

// out[c][r] = bf16(in[r][c]) ; in is R x Cdim row-major
__global__ __launch_bounds__(256) void transpose_f32_bf16(const float* __restrict__ in,
                                                          u16* __restrict__ out,
                                                          int R, int Cdim) {
  __shared__ float tile[64][65];
  const int c0 = blockIdx.x * 64, r0 = blockIdx.y * 64;
  const int tx = threadIdx.x & 63, ty = threadIdx.x >> 6;
#pragma unroll
  for (int i = 0; i < 64; i += 4)
    tile[ty + i][tx] = in[(size_t)(r0 + ty + i) * Cdim + c0 + tx];
  __syncthreads();
#pragma unroll
  for (int i = 0; i < 64; i += 4)
    out[(size_t)(c0 + ty + i) * R + r0 + tx] = f2bf(tile[tx][ty + i]);
}

// V slice of qkv (fp32 [T][4096], cols 3072..4095) -> Vt bf16 [kvh][d][t]
// Also zeroes the attn work-queue counter (runs after GEMM1, before attn).
__global__ __launch_bounds__(256) void v_transpose(const float* __restrict__ qkv,
                                                   u16* __restrict__ Vt,
                                                   unsigned* __restrict__ counter) {
  if (blockIdx.x == 0 && blockIdx.y == 0 && blockIdx.z == 0 && threadIdx.x == 0)
    *counter = 0u;
  __shared__ float tile[64][65];
  const int h = blockIdx.x, t0 = blockIdx.y * 64, d0 = blockIdx.z * 64;
  const int tx = threadIdx.x & 63, ty = threadIdx.x >> 6;
#pragma unroll
  for (int i = 0; i < 64; i += 4)
    tile[ty + i][tx] = qkv[(size_t)(t0 + ty + i) * 4096 + (NH + NKV) * DH + h * DH + d0 + tx];
  __syncthreads();
#pragma unroll
  for (int i = 0; i < 64; i += 4)
    Vt[((size_t)h * DH + d0 + ty + i) * T_TOK + t0 + tx] = f2bf(tile[tx][ty + i]);
}

// ------------------------------------------------- per-head RMSNorm + RoPE
__global__ __launch_bounds__(64) void qk_norm_rope(const float* __restrict__ qkv,
                                                   const int* __restrict__ pos,
                                                   const float* __restrict__ qw,
                                                   const float* __restrict__ kw,
                                                   u16* __restrict__ Qg,
                                                   u16* __restrict__ Kg) {
  const int t = blockIdx.x, slot = blockIdx.y, j = threadIdx.x;
  const float* src = qkv + (size_t)t * 4096 + slot * 128;
  float x1 = src[j], x2 = src[j + 64];
  float ss = x1 * x1 + x2 * x2;
#pragma unroll
  for (int m = 1; m < 64; m <<= 1) ss += __shfl_xor(ss, m);
  float r = rsqrtf(ss * (1.0f / 128.0f) + 1e-6f);
  const bool isq = slot < NH;
  const float* w = isq ? qw : kw;
  float xn1 = x1 * r * w[j], xn2 = x2 * r * w[j + 64];
  float fp = (float)pos[t];
  float inv_freq = exp2f(-(float)j * (13.287712379549449f / 64.0f)); // 10000^(-j/64)
  float ang = fp * inv_freq;
  float sn, cs;
  sincosf(ang, &sn, &cs);
  float o1 = xn1 * cs - xn2 * sn;
  float o2 = xn2 * cs + xn1 * sn;
  if (isq) {
    size_t b = ((size_t)slot * T_TOK + t) * DH;
    Qg[b + j] = f2bf(o1); Qg[b + 64 + j] = f2bf(o2);
  } else {
    size_t b = ((size_t)(slot - NH) * T_TOK + t) * DH;
    Kg[b + j] = f2bf(o1); Kg[b + 64 + j] = f2bf(o2);
  }
}

// ------------------------------------------------------------------- GEMM
// C[M][N] fp32 = A[M][K] bf16 row-major  x  Bt[N][K] bf16 row-major (B^T).
__global__ __launch_bounds__(256) void gemm_bf16(const u16* __restrict__ A,
                                                 const u16* __restrict__ Bt,
                                                 float* __restrict__ C,
                                                 int M, int N, int K) {
  __shared__ u16 Alds[128 * 32];
  __shared__ u16 Blds[128 * 32];
  const int m0 = blockIdx.y * 128, n0 = blockIdx.x * 128;
  const int wave = threadIdx.x >> 6, lane = threadIdx.x & 63;
  const int l15 = lane & 15, quad = lane >> 4;
  const int wr = wave >> 1, wc = wave & 1;

  const f32x4 zero = {0.f, 0.f, 0.f, 0.f};
  f32x4 acc[4][4];
#pragma unroll
  for (int i = 0; i < 4; ++i)
#pragma unroll
    for (int j = 0; j < 4; ++j) acc[i][j] = zero;

  for (int k0 = 0; k0 < K; k0 += 32) {
    __syncthreads();
#pragma unroll
    for (int c = 0; c < 2; ++c) {
      int chunk = wave * 2 + c;
      int slot = chunk * 64 + lane;   // 16B slots, 4 per row of 32 bf16
      int row = slot >> 2;
      int g = (slot & 3) ^ (row & 3); // swizzled source group
      gload16(A + (size_t)(m0 + row) * K + k0 + g * 8, &Alds[chunk * 512]);
      gload16(Bt + (size_t)(n0 + row) * K + k0 + g * 8, &Blds[chunk * 512]);
    }
    __syncthreads();
    bf16x8 af[4], bfr[4];
#pragma unroll
    for (int mt = 0; mt < 4; ++mt) {
      int r = wr * 64 + mt * 16 + l15;
      af[mt] = *(const bf16x8*)&Alds[r * 32 + ((quad ^ (r & 3)) * 8)];
    }
#pragma unroll
    for (int nt = 0; nt < 4; ++nt) {
      int r = wc * 64 + nt * 16 + l15;
      bfr[nt] = *(const bf16x8*)&Blds[r * 32 + ((quad ^ (r & 3)) * 8)];
    }
#pragma unroll
    for (int mt = 0; mt < 4; ++mt)
#pragma unroll
      for (int nt = 0; nt < 4; ++nt)
        acc[mt][nt] = __builtin_amdgcn_mfma_f32_16x16x32_bf16(af[mt], bfr[nt], acc[mt][nt], 0, 0, 0);
  }
#pragma unroll
  for (int mt = 0; mt < 4; ++mt)
#pragma unroll
    for (int nt = 0; nt < 4; ++nt)
#pragma unroll
      for (int r = 0; r < 4; ++r)
        C[(size_t)(m0 + wr * 64 + mt * 16 + quad * 4 + r) * N + n0 + wc * 64 + nt * 16 + l15] =
            acc[mt][nt][r];
}

// ------------------------------------------------------------- flash attn
// Flash-decode + persistent work queue. 1024 items = (h, qt64, khalf),
// each <=16 k-iterations, grabbed longest-first via device atomic by 768
// persistent blocks (3/CU at 41KB LDS -> 37.5% occupancy, placement-
// independent LPT balance). K-loop body = round-1's verified LDS-staged
// version. Partials (unnormalized O, m, l) -> ws; merged by attn_merge.
__global__ __launch_bounds__(256) void attn_kernel(const u16* __restrict__ Qg,
                                                   const u16* __restrict__ Kg,
                                                   const u16* __restrict__ Vtg,
                                                   float* __restrict__ Opart,
                                                   float* __restrict__ Mpart,
                                                   float* __restrict__ Lpart,
                                                   unsigned* __restrict__ counter) {
  __shared__ u16 Klds[64 * 128];       // [s][d], 16B group g at g^(s&15)
  __shared__ u16 Vlds[128 * 64];       // [d][s], 16B group g at g^(d&7)
  __shared__ u16 Plds[4][16 * 72];     // per-wave P, padded stride 72
  __shared__ unsigned item_s;
  const int wave = threadIdx.x >> 6, lane = threadIdx.x & 63;
  const int l15 = lane & 15, quad = lane >> 4;
  u16* Pw = &Plds[wave][0];
  const float CSC = 0.088388347648318447f * 1.4426950408889634f; // scale*log2e
  const f32x4 zero = {0.f, 0.f, 0.f, 0.f};
  const float4 zero4 = {0.f, 0.f, 0.f, 0.f};

  for (;;) {
    __syncthreads();                    // protect item_s + LDS reuse
    if (threadIdx.x == 0) item_s = atomicAdd(counter, 1u);
    __syncthreads();
    const unsigned item = item_s;
    if (item >= 1024u) break;
    const int qt = 31 - (int)(item >> 5);     // longest-first
    const int s  = (int)(item >> 4) & 1;
    const int h  = (int)item & 15;
    const int kvh = h >> 1;
    const int slot = (h * 32 + qt) * 2 + s;
    const int j0 = s ? (qt + 2) >> 1 : 0;
    const int j1 = s ? qt + 1 : (qt + 2) >> 1;

    float* Oslot = Opart + (size_t)slot * (64 * 128);

    if (j0 >= j1) {                     // empty split (qt==0, s==1)
      for (int t = threadIdx.x; t < 64 * 128 / 4; t += 256) ((float4*)Oslot)[t] = zero4;
      if (threadIdx.x < 64) {
        Mpart[slot * 64 + threadIdx.x] = -INFINITY;
        Lpart[slot * 64 + threadIdx.x] = 0.f;
      }
      continue;
    }

    const u16* Qh = Qg + (size_t)h * T_TOK * DH;
    const u16* Kh = Kg + (size_t)kvh * T_TOK * DH;
    const u16* Vh = Vtg + (size_t)kvh * DH * T_TOK;
    const int qrow0 = qt * 64 + wave * 16;

    bf16x8 qf[4];
#pragma unroll
    for (int ks = 0; ks < 4; ++ks)
      qf[ks] = *(const bf16x8*)(Qh + (size_t)(qrow0 + l15) * DH + ks * 32 + quad * 8);

    f32x4 oacc[8];
#pragma unroll
    for (int i = 0; i < 8; ++i) oacc[i] = zero;
    float m_i[4] = {-INFINITY, -INFINITY, -INFINITY, -INFINITY};
    float l_i[4] = {0.f, 0.f, 0.f, 0.f};

    for (int j = j0; j < j1; ++j) {
      __syncthreads();                  // previous tile's LDS reads done
#pragma unroll
      for (int c = 0; c < 4; ++c) {
        int chunk = wave * 4 + c;
        int sl = chunk * 64 + lane;
        {
          int ss = sl >> 4;             // 16 slots per 256B K row
          int g = (sl & 15) ^ (ss & 15);
          gload16(Kh + ((size_t)(j * 64 + ss)) * DH + g * 8, &Klds[chunk * 512]);
        }
        {
          int d = sl >> 3;              // 8 slots per 128B V row
          int g = (sl & 7) ^ (d & 7);
          gload16(Vh + (size_t)d * T_TOK + j * 64 + g * 8, &Vlds[chunk * 512]);
        }
      }
      __syncthreads();                  // staging complete

      // S = Q K^T
      f32x4 sacc[4];
#pragma unroll
      for (int nt = 0; nt < 4; ++nt) sacc[nt] = zero;
#pragma unroll
      for (int nt = 0; nt < 4; ++nt) {
        int sr = nt * 16 + l15;
#pragma unroll
        for (int ks = 0; ks < 4; ++ks) {
          bf16x8 kf = *(const bf16x8*)&Klds[sr * 128 + (((ks * 4 + quad) ^ (sr & 15)) * 8)];
          sacc[nt] = __builtin_amdgcn_mfma_f32_16x16x32_bf16(qf[ks], kf, sacc[nt], 0, 0, 0);
        }
      }

      if (j == qt) {                    // diagonal tile: causal mask
#pragma unroll
        for (int nt = 0; nt < 4; ++nt)
#pragma unroll
          for (int r = 0; r < 4; ++r) {
            int col = j * 64 + nt * 16 + l15;
            int row = qrow0 + quad * 4 + r;
            if (col > row) sacc[nt][r] = -INFINITY;
          }
      }

      // online softmax (rows = quad*4+r, reduce across 16-lane col group)
      float mx[4];
#pragma unroll
      for (int r = 0; r < 4; ++r)
        mx[r] = fmaxf(fmaxf(sacc[0][r], sacc[1][r]), fmaxf(sacc[2][r], sacc[3][r]));
#pragma unroll
      for (int msk = 1; msk < 16; msk <<= 1)
#pragma unroll
        for (int r = 0; r < 4; ++r) mx[r] = fmaxf(mx[r], __shfl_xor(mx[r], msk));

      float alpha[4], lsum[4];
#pragma unroll
      for (int r = 0; r < 4; ++r) {
        float mn = fmaxf(m_i[r], mx[r]);
        alpha[r] = exp2f((m_i[r] - mn) * CSC);
        m_i[r] = mn;
        lsum[r] = 0.f;
      }
#pragma unroll
      for (int nt = 0; nt < 4; ++nt)
#pragma unroll
        for (int r = 0; r < 4; ++r) {
          float pv = exp2f((sacc[nt][r] - m_i[r]) * CSC);
          lsum[r] += pv;
          Pw[(quad * 4 + r) * 72 + nt * 16 + l15] = f2bf(pv);
        }
#pragma unroll
      for (int msk = 1; msk < 16; msk <<= 1)
#pragma unroll
        for (int r = 0; r < 4; ++r) lsum[r] += __shfl_xor(lsum[r], msk);
#pragma unroll
      for (int r = 0; r < 4; ++r) l_i[r] = l_i[r] * alpha[r] + lsum[r];
      {
        f32x4 av = {alpha[0], alpha[1], alpha[2], alpha[3]};
#pragma unroll
        for (int ot = 0; ot < 8; ++ot) oacc[ot] *= av;
      }

      // O += P V
      bf16x8 pf[2];
#pragma unroll
      for (int ks = 0; ks < 2; ++ks)
        pf[ks] = *(const bf16x8*)&Pw[l15 * 72 + ks * 32 + quad * 8];
#pragma unroll
      for (int ot = 0; ot < 8; ++ot) {
        int d = ot * 16 + l15;
#pragma unroll
        for (int ks = 0; ks < 2; ++ks) {
          bf16x8 vf = *(const bf16x8*)&Vlds[d * 64 + (((ks * 4 + quad) ^ (d & 7)) * 8)];
          oacc[ot] = __builtin_amdgcn_mfma_f32_16x16x32_bf16(pf[ks], vf, oacc[ot], 0, 0, 0);
        }
      }
    }

    // partial epilogue: UNNORMALIZED O + (m, l) per row
#pragma unroll
    for (int ot = 0; ot < 8; ++ot)
#pragma unroll
      for (int r = 0; r < 4; ++r)
        Oslot[(wave * 16 + quad * 4 + r) * 128 + ot * 16 + l15] = oacc[ot][r];
    if (l15 == 0) {
#pragma unroll
      for (int r = 0; r < 4; ++r) {
        int row = wave * 16 + quad * 4 + r;
        Mpart[slot * 64 + row] = m_i[r];
        Lpart[slot * 64 + row] = l_i[r];
      }
    }
  }
}

// merge the two k-halves of each (h, qt): O = sum w_s * O_s, / sum w_s * l_s
__global__ __launch_bounds__(256) void attn_merge(const float* __restrict__ Opart,
                                                  const float* __restrict__ Mpart,
                                                  const float* __restrict__ Lpart,
                                                  u16* __restrict__ Og) {
  const int b = blockIdx.x;
  const int h = b & 15, qt = b >> 4;
  const int slot0 = (h * 32 + qt) * 2, slot1 = slot0 + 1;
  const float CSC = 0.088388347648318447f * 1.4426950408889634f;
  const float4* O0 = (const float4*)(Opart + (size_t)slot0 * (64 * 128));
  const float4* O1 = (const float4*)(Opart + (size_t)slot1 * (64 * 128));
#pragma unroll
  for (int it = 0; it < 8; ++it) {
    int idx = it * 256 + threadIdx.x;   // 0..2047 float4s (64 rows x 32)
    int r = idx >> 5, c4 = idx & 31;
    float m0 = Mpart[slot0 * 64 + r], m1 = Mpart[slot1 * 64 + r];
    float l0 = Lpart[slot0 * 64 + r], l1 = Lpart[slot1 * 64 + r];
    float ms = fmaxf(m0, m1);
    float w0 = exp2f((m0 - ms) * CSC), w1 = exp2f((m1 - ms) * CSC);
    float rl = 1.0f / (l0 * w0 + l1 * w1);
    float4 a = O0[idx], c = O1[idx];
    int row = qt * 64 + r, col = c4 * 4;
    u16* dst = Og + (size_t)row * (NH * DH) + h * DH + col;
    dst[0] = f2bf((a.x * w0 + c.x * w1) * rl);
    dst[1] = f2bf((a.y * w0 + c.y * w1) * rl);
    dst[2] = f2bf((a.z * w0 + c.z * w1) * rl);
    dst[3] = f2bf((a.w * w0 + c.w * w1) * rl);
  }
}

// ------------------------------------------------------------------ launch
extern "C" void kernel_launch(void* const* d_in, const int* in_sizes, int n_in,
                              void* d_out, int out_size, void* d_ws, size_t ws_size,
                              hipStream_t stream) {
  (void)in_sizes; (void)n_in; (void)out_size; (void)ws_size;
  const int* positions = (const int*)d_in[0];
  const float* hidden  = (const float*)d_in[1];
  const float* w_qkv   = (const float*)d_in[2];
  const float* w_o     = (const float*)d_in[3];
  const float* q_norm  = (const float*)d_in[4];
  const float* k_norm  = (const float*)d_in[5];
  float* out = (float*)d_out;

  char* ws = (char*)d_ws;
  u16*   Xb    = (u16*)(ws);                          //  8 MB  bf16 hidden [T][HID]
  u16*   WqkvT = (u16*)(ws + ( 8ull << 20));          // 16 MB  bf16 [4096][2048]
  u16*   WoT   = (u16*)(ws + (24ull << 20));          //  8 MB  bf16 [2048][2048]
  float* QKV   = (float*)(ws + (32ull << 20));        // 32 MB  fp32 [T][4096]
  u16*   Qg    = (u16*)(ws + (64ull << 20));          //  8 MB  bf16 [NH][T][D]
  u16*   Kg    = (u16*)(ws + (72ull << 20));          //  4 MB  bf16 [NKV][T][D]
  u16*   Vt    = (u16*)(ws + (76ull << 20));          //  4 MB  bf16 [NKV][D][T]
  u16*   AttnO = (u16*)(ws + (80ull << 20));          //  8 MB  bf16 [T][NH*D]
  // dead-region reuse (valid after their producers finish):
  float* Opart = QKV;                                 // 32 MB, free after rope+vtrans
  float* Mpart   = (float*)(ws);                      // 256 KB, in dead Xb (free after GEMM1)
  float* Lpart   = (float*)(ws + (256ull << 10));     // 256 KB
  unsigned* ctr  = (unsigned*)(ws + (512ull << 10));  // 4 B

  f32_to_bf16_vec<<<dim3((T_TOK * HIDDEN / 4 + 255) / 256), 256, 0, stream>>>(
      hidden, Xb, T_TOK * HIDDEN / 4);
  transpose_f32_bf16<<<dim3(4096 / 64, HIDDEN / 64), 256, 0, stream>>>(w_qkv, WqkvT, HIDDEN, 4096);
  transpose_f32_bf16<<<dim3(HIDDEN / 64, 2048 / 64), 256, 0, stream>>>(w_o, WoT, 2048, HIDDEN);

  gemm_bf16<<<dim3(4096 / 128, T_TOK / 128), 256, 0, stream>>>(Xb, WqkvT, QKV, T_TOK, 4096, HIDDEN);

  qk_norm_rope<<<dim3(T_TOK, NH + NKV), 64, 0, stream>>>(QKV, positions, q_norm, k_norm, Qg, Kg);
  v_transpose<<<dim3(NKV, T_TOK / 64, DH / 64), 256, 0, stream>>>(QKV, Vt, ctr);

  attn_kernel<<<dim3(768), 256, 0, stream>>>(Qg, Kg, Vt, Opart, Mpart, Lpart, ctr);
  attn_merge<<<dim3(512), 256, 0, stream>>>(Opart, Mpart, Lpart, AttnO);

  gemm_bf16<<<dim3(HIDDEN / 128, T_TOK / 128), 256, 0, stream>>>(AttnO, WoT, out, T_TOK, HIDDEN, NH * DH);
}